// Round 3
// baseline (387.568 us; speedup 1.0000x reference)
//
#include <hip/hip_runtime.h>
#include <hip/hip_bf16.h>

#define N_NODES 50000
#define N_EDGES 800000
#define IN_DIM 64
#define HID_DIM 128
#define OUT_DIM 64
#define NGRP 8
#define NE8 (NGRP * N_NODES)                  // 400000 group-major degree entries
#define NBLK8 ((NE8 + 255) / 256)             // 1563 scan blocks

// ---- device-global scratch (no ws_size dependence) ----
__device__ int g_in_f32;
__device__ int g_is64;
__device__ int g_src[N_EDGES];
__device__ int g_dst[N_EDGES];
__device__ int g_csr[N_EDGES];
__device__ int g_deg8[NE8];                   // [g][v] group-major
__device__ int g_rowptr8[NE8 + 1];
__device__ int g_cursor8[NE8];
__device__ int g_bsum[NBLK8];
__device__ int g_boff[NBLK8];
__device__ float g_dinv[N_NODES];
__device__ __align__(16) float g_hs1[(size_t)N_NODES * HID_DIM];   // aggz (N*64), later hs2 (N*64)
__device__ __align__(16) float g_agg1[(size_t)N_NODES * HID_DIM];  // zs (N*64), later h (N*128)

__device__ __forceinline__ float loadx(const void* p, int i, int f32) {
    if (f32) return ((const float*)p)[i];
    unsigned int u = ((unsigned int)((const unsigned short*)p)[i]) << 16;
    return __uint_as_float(u);
}

// ---- zero the per-group degree counters ----
__global__ void zerodeg_kernel() {
    int i = blockIdx.x * blockDim.x + threadIdx.x;
    if (i < NE8) g_deg8[i] = 0;
}

// ---- dtype / index-width detection (data-driven, deterministic) ----
__global__ void detect_kernel(const unsigned short* __restrict__ zw,
                              const unsigned int* __restrict__ ew, int E) {
    __shared__ int s_f32, s_nz;
    if (threadIdx.x == 0) { s_f32 = 0; s_nz = 0; }
    __syncthreads();
    int hit = 0;
    for (int k = 0; k < 64; k++) {
        int i = 2 * ((threadIdx.x * 64 + k) * 97);
        if (((zw[i] >> 7) & 0xFF) == 0xFF) hit = 1;
    }
    if (hit) atomicOr(&s_f32, 1);
    int nz = 0;
    int step = E / 4096;
    for (int k = 0; k < 4; k++) {
        int idx = 1 + 2 * ((threadIdx.x * 4 + k) * step);
        if (ew[idx] != 0) nz = 1;
    }
    if (nz) atomicOr(&s_nz, 1);
    __syncthreads();
    if (threadIdx.x == 0) { g_in_f32 = s_f32; g_is64 = (s_nz == 0) ? 1 : 0; }
}

// ---- normalize edge_index to int32 + fused per-group degree count ----
// group of edge e = blockIdx&7 -> one XCD per group under round-robin mapping
__global__ void convert_kernel(const void* __restrict__ ei, int N, int E) {
    int e = blockIdx.x * blockDim.x + threadIdx.x;
    if (e < E) {
        int s, d;
        if (g_is64) {
            const long long* p = (const long long*)ei;
            s = (int)p[e];
            d = (int)p[E + e];
        } else {
            const int* p = (const int*)ei;
            s = p[e];
            d = p[E + e];
        }
        g_src[e] = s;
        g_dst[e] = d;
        int g = blockIdx.x & (NGRP - 1);
        atomicAdd(&g_deg8[g * N + d], 1);
    }
}

// ---- dinv from summed per-group degrees ----
__global__ void dinv_kernel(int N) {
    int v = blockIdx.x * blockDim.x + threadIdx.x;
    if (v < N) {
        int s = 0;
#pragma unroll
        for (int g = 0; g < NGRP; g++) s += g_deg8[g * N + v];
        g_dinv[v] = rsqrtf((float)s + 1.0f);  // +1 = self loop
    }
}

// ---- phase A: per-block exclusive scan of deg8 ----
__global__ __launch_bounds__(256) void localscan_kernel(int NE) {
    __shared__ int sc[256];
    int t = threadIdx.x;
    int idx = blockIdx.x * 256 + t;
    int d = (idx < NE) ? g_deg8[idx] : 0;
    sc[t] = d;
    __syncthreads();
    for (int off = 1; off < 256; off <<= 1) {
        int v = (t >= off) ? sc[t - off] : 0;
        __syncthreads();
        sc[t] += v;
        __syncthreads();
    }
    if (idx < NE) g_rowptr8[idx] = sc[t] - d;  // local exclusive prefix
    if (t == 255) g_bsum[blockIdx.x] = sc[255];
}

// ---- phase B: scan block sums (chunked with carry) ----
__global__ __launch_bounds__(1024) void bscan_kernel(int NB, int NE, int E) {
    __shared__ int sc[1024];
    int t = threadIdx.x;
    int carry = 0;
    for (int c0 = 0; c0 < NB; c0 += 1024) {
        int i = c0 + t;
        int v = (i < NB) ? g_bsum[i] : 0;
        sc[t] = v;
        __syncthreads();
        for (int off = 1; off < 1024; off <<= 1) {
            int u = (t >= off) ? sc[t - off] : 0;
            __syncthreads();
            sc[t] += u;
            __syncthreads();
        }
        if (i < NB) g_boff[i] = carry + sc[t] - v;
        carry += sc[1023];
        __syncthreads();
    }
    if (t == 0) g_rowptr8[NE] = E;
}

// ---- phase C: add block offsets; finalize rowptr8 + cursor8 ----
__global__ __launch_bounds__(256) void addoff_kernel(int NE) {
    int idx = blockIdx.x * 256 + threadIdx.x;
    if (idx < NE) {
        int base = g_rowptr8[idx] + g_boff[blockIdx.x];
        g_rowptr8[idx] = base;
        g_cursor8[idx] = base;
    }
}

// ---- scatter edges into group-partitioned CSR buckets ----
__global__ void scatter_kernel(int N, int E) {
    int e = blockIdx.x * blockDim.x + threadIdx.x;
    if (e < E) {
        int g = blockIdx.x & (NGRP - 1);
        int pos = atomicAdd(&g_cursor8[g * N + g_dst[e]], 1);
        g_csr[pos] = g_src[e];
    }
}

// ---- zs[row,:] = z[row,:] * dinv[row]  (also dtype-normalizes to f32) -> g_agg1 ----
__global__ void zscale_kernel(const void* __restrict__ z, int N) {
    int i = blockIdx.x * blockDim.x + threadIdx.x;
    if (i < N * IN_DIM) {
        int row = i >> 6;
        g_agg1[i] = loadx(z, i, g_in_f32) * g_dinv[row];
    }
}

// ---- layer-1 aggregation on 64-dim zs (S z): wave per node, 8 group ranges -> g_hs1 ----
__global__ void aggz_kernel(int N) {
    int wid = (blockIdx.x * blockDim.x + threadIdx.x) >> 6;
    if (wid >= N) return;
    wid = __builtin_amdgcn_readfirstlane(wid);
    int lane = threadIdx.x & 63;
    const float* zs = g_agg1;
    float a0 = zs[(size_t)wid * 64 + lane];  // self-loop term
    float a1 = 0.f, a2 = 0.f, a3 = 0.f;
    for (int g = 0; g < NGRP; g++) {
        int beg = g_rowptr8[g * N + wid], end = g_rowptr8[g * N + wid + 1];
        int e = beg;
        for (; e + 4 <= end; e += 4) {
            int s0 = g_csr[e], s1 = g_csr[e + 1], s2 = g_csr[e + 2], s3 = g_csr[e + 3];
            a0 += zs[(size_t)s0 * 64 + lane];
            a1 += zs[(size_t)s1 * 64 + lane];
            a2 += zs[(size_t)s2 * 64 + lane];
            a3 += zs[(size_t)s3 * 64 + lane];
        }
        for (; e < end; e++) a0 += zs[(size_t)g_csr[e] * 64 + lane];
    }
    float acc = (a0 + a1) + (a2 + a3);
    g_hs1[(size_t)wid * 64 + lane] = acc * g_dinv[wid];
}

// ---- h = relu(aggz @ W1 + b1): 32 rows/block, 4x4 micro-tile -> g_agg1 (N x 128) ----
__global__ __launch_bounds__(256) void gemm1_kernel(const void* __restrict__ W1,
                                                    const void* __restrict__ b1, int N) {
    __shared__ float Ws[IN_DIM * HID_DIM];   // 32 KB
    __shared__ float Zs[IN_DIM * 33];        // transposed 64k x 32r, pad 33
    int t = threadIdx.x;
    int f32 = g_in_f32;
    for (int i = t; i < IN_DIM * HID_DIM; i += 256) Ws[i] = loadx(W1, i, f32);
    int row0 = blockIdx.x * 32;
    const float* aggz = g_hs1;
    for (int i = t; i < 32 * IN_DIM; i += 256) {
        int r = i >> 6, k = i & 63;
        int row = row0 + r;
        Zs[k * 33 + r] = (row < N) ? aggz[(size_t)row * IN_DIM + k] : 0.f;
    }
    __syncthreads();
    int cg = t & 31, rg = t >> 5;  // 32 colgroups x 8 rowgroups
    int c0 = cg * 4, r0 = rg * 4;
    float acc[4][4] = {};
#pragma unroll 8
    for (int k = 0; k < IN_DIM; k++) {
        float b[4];
        *(float4*)b = *(const float4*)&Ws[k * HID_DIM + c0];
        float a[4];
        a[0] = Zs[k * 33 + r0];
        a[1] = Zs[k * 33 + r0 + 1];
        a[2] = Zs[k * 33 + r0 + 2];
        a[3] = Zs[k * 33 + r0 + 3];
#pragma unroll
        for (int i = 0; i < 4; i++)
#pragma unroll
            for (int j = 0; j < 4; j++) acc[i][j] = fmaf(a[i], b[j], acc[i][j]);
    }
    float bias[4];
#pragma unroll
    for (int j = 0; j < 4; j++) bias[j] = loadx(b1, c0 + j, f32);
#pragma unroll
    for (int i = 0; i < 4; i++) {
        int row = row0 + r0 + i;
        if (row < N) {
            float4 v;
            v.x = fmaxf(acc[i][0] + bias[0], 0.f);
            v.y = fmaxf(acc[i][1] + bias[1], 0.f);
            v.z = fmaxf(acc[i][2] + bias[2], 0.f);
            v.w = fmaxf(acc[i][3] + bias[3], 0.f);
            *(float4*)&g_agg1[(size_t)row * HID_DIM + c0] = v;
        }
    }
}

// ---- hs2 = (h @ W2) * dinv: 64 rows/block, K split 2x64, 4x4 micro-tile -> g_hs1 ----
__global__ __launch_bounds__(256) void gemm2_kernel(const void* __restrict__ W2, int N) {
    __shared__ float Ws[HID_DIM * OUT_DIM];  // 32 KB
    __shared__ float Zs[64 * 65];            // transposed 64k x 64r, pad 65
    int t = threadIdx.x;
    int f32 = g_in_f32;
    for (int i = t; i < HID_DIM * OUT_DIM; i += 256) Ws[i] = loadx(W2, i, f32);
    int row0 = blockIdx.x * 64;
    int cg = t & 15, rg = t >> 4;  // 16 colgroups x 16 rowgroups
    int c0 = cg * 4, r0 = rg * 4;
    float acc[4][4] = {};
    for (int kh = 0; kh < 2; kh++) {
        __syncthreads();
        for (int i = t; i < 64 * 64; i += 256) {
            int r = i >> 6, k2 = i & 63;
            int row = row0 + r;
            Zs[k2 * 65 + r] = (row < N) ? g_agg1[(size_t)row * HID_DIM + kh * 64 + k2] : 0.f;
        }
        __syncthreads();
#pragma unroll 8
        for (int k2 = 0; k2 < 64; k2++) {
            float b[4];
            *(float4*)b = *(const float4*)&Ws[(kh * 64 + k2) * OUT_DIM + c0];
            float a[4];
            a[0] = Zs[k2 * 65 + r0];
            a[1] = Zs[k2 * 65 + r0 + 1];
            a[2] = Zs[k2 * 65 + r0 + 2];
            a[3] = Zs[k2 * 65 + r0 + 3];
#pragma unroll
            for (int i = 0; i < 4; i++)
#pragma unroll
                for (int j = 0; j < 4; j++) acc[i][j] = fmaf(a[i], b[j], acc[i][j]);
        }
    }
#pragma unroll
    for (int i = 0; i < 4; i++) {
        int row = row0 + r0 + i;
        if (row < N) {
            float dn = g_dinv[row];
            float4 v;
            v.x = acc[i][0] * dn;
            v.y = acc[i][1] * dn;
            v.z = acc[i][2] * dn;
            v.w = acc[i][3] * dn;
            *(float4*)&g_hs1[(size_t)row * OUT_DIM + c0] = v;
        }
    }
}

// ---- layer-2 aggregation: wave per node, 8 group ranges; fused bias + store ----
__global__ void agg2_kernel(const void* __restrict__ b2, void* __restrict__ out, int N) {
    int wid = (blockIdx.x * blockDim.x + threadIdx.x) >> 6;
    if (wid >= N) return;
    wid = __builtin_amdgcn_readfirstlane(wid);
    int lane = threadIdx.x & 63;
    const float* hs = g_hs1;  // row = 64 floats
    float a0 = hs[(size_t)wid * 64 + lane];  // self-loop term
    float a1 = 0.f, a2 = 0.f, a3 = 0.f;
    for (int g = 0; g < NGRP; g++) {
        int beg = g_rowptr8[g * N + wid], end = g_rowptr8[g * N + wid + 1];
        int e = beg;
        for (; e + 4 <= end; e += 4) {
            int s0 = g_csr[e], s1 = g_csr[e + 1], s2 = g_csr[e + 2], s3 = g_csr[e + 3];
            a0 += hs[(size_t)s0 * 64 + lane];
            a1 += hs[(size_t)s1 * 64 + lane];
            a2 += hs[(size_t)s2 * 64 + lane];
            a3 += hs[(size_t)s3 * 64 + lane];
        }
        for (; e < end; e++) a0 += hs[(size_t)g_csr[e] * 64 + lane];
    }
    float acc = (a0 + a1) + (a2 + a3);
    int f32 = g_in_f32;
    float v = acc * g_dinv[wid] + loadx(b2, lane, f32);
    if (f32) ((float*)out)[(size_t)wid * 64 + lane] = v;
    else ((__hip_bfloat16*)out)[(size_t)wid * 64 + lane] = __float2bfloat16(v);
}

extern "C" void kernel_launch(void* const* d_in, const int* in_sizes, int n_in,
                              void* d_out, int out_size, void* d_ws, size_t ws_size,
                              hipStream_t stream) {
    const void* z  = d_in[0];
    const void* ei = d_in[1];
    const void* W1 = d_in[2];
    const void* b1 = d_in[3];
    const void* W2 = d_in[4];
    const void* b2 = d_in[5];

    const int N = in_sizes[0] / IN_DIM;  // 50000
    const int E = in_sizes[1] / 2;       // 800000
    const int NE = NGRP * N;             // 400000

    zerodeg_kernel<<<NBLK8, 256, 0, stream>>>();
    detect_kernel<<<1, 256, 0, stream>>>((const unsigned short*)z, (const unsigned int*)ei, E);
    convert_kernel<<<(E + 255) / 256, 256, 0, stream>>>(ei, N, E);
    dinv_kernel<<<(N + 255) / 256, 256, 0, stream>>>(N);
    localscan_kernel<<<(NE + 255) / 256, 256, 0, stream>>>(NE);
    bscan_kernel<<<1, 1024, 0, stream>>>((NE + 255) / 256, NE, E);
    addoff_kernel<<<(NE + 255) / 256, 256, 0, stream>>>(NE);
    scatter_kernel<<<(E + 255) / 256, 256, 0, stream>>>(N, E);

    zscale_kernel<<<(N * IN_DIM + 255) / 256, 256, 0, stream>>>(z, N);
    aggz_kernel<<<(N * 64 + 255) / 256, 256, 0, stream>>>(N);
    gemm1_kernel<<<(N + 31) / 32, 256, 0, stream>>>(W1, b1, N);

    gemm2_kernel<<<(N + 63) / 64, 256, 0, stream>>>(W2, N);
    agg2_kernel<<<(N * 64 + 255) / 256, 256, 0, stream>>>(b2, d_out, N);
}

// Round 4
// 322.290 us; speedup vs baseline: 1.2025x; 1.2025x over previous
//
#include <hip/hip_runtime.h>
#include <hip/hip_bf16.h>

#define N_NODES 50000
#define N_EDGES 800000
#define IN_DIM 64
#define HID_DIM 128
#define OUT_DIM 64
#define NGRP 8
#define NE8 (NGRP * N_NODES)                  // 400000 group-major degree entries
#define NBLK8 ((NE8 + 255) / 256)             // 1563 scan blocks
#define MAXE 128                              // per-wave compacted edge cap

// ---- device-global scratch (no ws_size dependence) ----
__device__ int g_in_f32;
__device__ int g_is64;
__device__ int g_src[N_EDGES];
__device__ int g_dst[N_EDGES];
__device__ int g_csr[N_EDGES];
__device__ int g_deg8[NE8];                   // [g][v] group-major
__device__ int g_rowptr8[NE8 + 1];
__device__ int g_cursor8[NE8];
__device__ int g_bsum[NBLK8];
__device__ int g_boff[NBLK8];
__device__ float g_dinv[N_NODES];
__device__ __align__(16) float g_W1f[IN_DIM * HID_DIM];
__device__ __align__(16) float g_W2f[HID_DIM * OUT_DIM];
__device__ __align__(16) float g_b1f[HID_DIM];
__device__ __align__(16) float g_b2f[OUT_DIM];
__device__ __align__(16) float g_hs1[(size_t)N_NODES * HID_DIM];   // aggz out (N*64), later hs2 (N*64)
__device__ __align__(16) float g_agg1[(size_t)N_NODES * HID_DIM];  // h (N*128)

__device__ __forceinline__ float loadx(const void* p, int i, int f32) {
    if (f32) return ((const float*)p)[i];
    unsigned int u = ((unsigned int)((const unsigned short*)p)[i]) << 16;
    return __uint_as_float(u);
}

// ---- dtype / index-width detection (data-driven, deterministic) ----
__global__ void detect_kernel(const unsigned short* __restrict__ zw,
                              const unsigned int* __restrict__ ew, int E) {
    __shared__ int s_f32, s_nz;
    if (threadIdx.x == 0) { s_f32 = 0; s_nz = 0; }
    __syncthreads();
    int hit = 0;
    for (int k = 0; k < 64; k++) {
        int i = 2 * ((threadIdx.x * 64 + k) * 97);
        if (((zw[i] >> 7) & 0xFF) == 0xFF) hit = 1;
    }
    if (hit) atomicOr(&s_f32, 1);
    int nz = 0;
    int step = E / 4096;
    for (int k = 0; k < 4; k++) {
        int idx = 1 + 2 * ((threadIdx.x * 4 + k) * step);
        if (ew[idx] != 0) nz = 1;
    }
    if (nz) atomicOr(&s_nz, 1);
    __syncthreads();
    if (threadIdx.x == 0) { g_in_f32 = s_f32; g_is64 = (s_nz == 0) ? 1 : 0; }
}

// ---- zero deg8 + convert weights/biases to f32 scratch (after detect) ----
__global__ void prep_kernel(const void* __restrict__ W1, const void* __restrict__ b1,
                            const void* __restrict__ W2, const void* __restrict__ b2) {
    int i = blockIdx.x * blockDim.x + threadIdx.x;
    if (i < NE8) g_deg8[i] = 0;
    int f32 = g_in_f32;
    if (i < IN_DIM * HID_DIM) g_W1f[i] = loadx(W1, i, f32);
    if (i < HID_DIM * OUT_DIM) g_W2f[i] = loadx(W2, i, f32);
    if (i < HID_DIM) g_b1f[i] = loadx(b1, i, f32);
    if (i < OUT_DIM) g_b2f[i] = loadx(b2, i, f32);
}

// ---- normalize edge_index to int32 + fused per-group degree count ----
__global__ void convert_kernel(const void* __restrict__ ei, int N, int E) {
    int e = blockIdx.x * blockDim.x + threadIdx.x;
    if (e < E) {
        int s, d;
        if (g_is64) {
            const long long* p = (const long long*)ei;
            s = (int)p[e];
            d = (int)p[E + e];
        } else {
            const int* p = (const int*)ei;
            s = p[e];
            d = p[E + e];
        }
        g_src[e] = s;
        g_dst[e] = d;
        int g = blockIdx.x & (NGRP - 1);
        atomicAdd(&g_deg8[g * N + d], 1);
    }
}

// ---- dinv from summed per-group degrees ----
__global__ void dinv_kernel(int N) {
    int v = blockIdx.x * blockDim.x + threadIdx.x;
    if (v < N) {
        int s = 0;
#pragma unroll
        for (int g = 0; g < NGRP; g++) s += g_deg8[g * N + v];
        g_dinv[v] = rsqrtf((float)s + 1.0f);  // +1 = self loop
    }
}

// ---- phase A: per-block exclusive scan of deg8 ----
__global__ __launch_bounds__(256) void localscan_kernel(int NE) {
    __shared__ int sc[256];
    int t = threadIdx.x;
    int idx = blockIdx.x * 256 + t;
    int d = (idx < NE) ? g_deg8[idx] : 0;
    sc[t] = d;
    __syncthreads();
    for (int off = 1; off < 256; off <<= 1) {
        int v = (t >= off) ? sc[t - off] : 0;
        __syncthreads();
        sc[t] += v;
        __syncthreads();
    }
    if (idx < NE) g_rowptr8[idx] = sc[t] - d;  // local exclusive prefix
    if (t == 255) g_bsum[blockIdx.x] = sc[255];
}

// ---- phase B: scan block sums, 8 values/thread serial + one 256-scan ----
__global__ __launch_bounds__(256) void bscan_kernel(int NB, int NE, int E) {
    __shared__ int sc[256];
    int t = threadIdx.x;
    int loc[8];
    int s = 0;
#pragma unroll
    for (int j = 0; j < 8; j++) {
        int i = t * 8 + j;
        int v = (i < NB) ? g_bsum[i] : 0;
        loc[j] = s;  // exclusive within chunk
        s += v;
    }
    sc[t] = s;
    __syncthreads();
    for (int off = 1; off < 256; off <<= 1) {
        int v = (t >= off) ? sc[t - off] : 0;
        __syncthreads();
        sc[t] += v;
        __syncthreads();
    }
    int excl = sc[t] - s;
#pragma unroll
    for (int j = 0; j < 8; j++) {
        int i = t * 8 + j;
        if (i < NB) g_boff[i] = excl + loc[j];
    }
    if (t == 0) g_rowptr8[NE] = E;
}

// ---- phase C: add block offsets; finalize rowptr8 + cursor8 ----
__global__ __launch_bounds__(256) void addoff_kernel(int NE) {
    int idx = blockIdx.x * 256 + threadIdx.x;
    if (idx < NE) {
        int base = g_rowptr8[idx] + g_boff[blockIdx.x];
        g_rowptr8[idx] = base;
        g_cursor8[idx] = base;
    }
}

// ---- scatter edges into group-partitioned CSR buckets (XCD write locality) ----
__global__ void scatter_kernel(int N, int E) {
    int e = blockIdx.x * blockDim.x + threadIdx.x;
    if (e < E) {
        int g = blockIdx.x & (NGRP - 1);
        int pos = atomicAdd(&g_cursor8[g * N + g_dst[e]], 1);
        g_csr[pos] = g_src[e];
    }
}

// ---- layer-1 agg fused with zscale: gather raw z, scale by dinv[src] in flight ----
// wave per node; 8 group ranges compacted into contiguous LDS list, 8-deep unroll
__global__ __launch_bounds__(256) void aggz_kernel(const void* __restrict__ z, int N) {
    __shared__ int idxbuf[4][MAXE];
    int wid = (blockIdx.x * blockDim.x + threadIdx.x) >> 6;
    if (wid >= N) return;
    int lane = threadIdx.x & 63;
    int w = threadIdx.x >> 6;
    int f32 = g_in_f32;
    int mybeg = 0, mycnt = 0;
    if (lane < NGRP) {
        mybeg = g_rowptr8[lane * N + wid];
        mycnt = g_rowptr8[lane * N + wid + 1] - mybeg;
    }
    int incl = mycnt;
#pragma unroll
    for (int off = 1; off < NGRP; off <<= 1) {
        int v = __shfl_up(incl, off, 64);
        if (lane >= off) incl += v;
    }
    int total = __shfl(incl, NGRP - 1, 64);
    int myoff = incl - mycnt;
    int* buf = idxbuf[w];
    float a0 = loadx(z, wid * IN_DIM + lane, f32) * g_dinv[wid];  // self loop
    float a1 = 0.f, a2 = 0.f, a3 = 0.f, a4 = 0.f, a5 = 0.f, a6 = 0.f, a7 = 0.f;
    if (total <= MAXE) {
        if (lane < NGRP) {
            for (int i = 0; i < mycnt; i++) buf[myoff + i] = g_csr[mybeg + i];
        }
        int j = 0;
        for (; j + 8 <= total; j += 8) {
            int i0 = buf[j], i1 = buf[j+1], i2 = buf[j+2], i3 = buf[j+3];
            int i4 = buf[j+4], i5 = buf[j+5], i6 = buf[j+6], i7 = buf[j+7];
            a0 += loadx(z, i0 * IN_DIM + lane, f32) * g_dinv[i0];
            a1 += loadx(z, i1 * IN_DIM + lane, f32) * g_dinv[i1];
            a2 += loadx(z, i2 * IN_DIM + lane, f32) * g_dinv[i2];
            a3 += loadx(z, i3 * IN_DIM + lane, f32) * g_dinv[i3];
            a4 += loadx(z, i4 * IN_DIM + lane, f32) * g_dinv[i4];
            a5 += loadx(z, i5 * IN_DIM + lane, f32) * g_dinv[i5];
            a6 += loadx(z, i6 * IN_DIM + lane, f32) * g_dinv[i6];
            a7 += loadx(z, i7 * IN_DIM + lane, f32) * g_dinv[i7];
        }
        if (j + 4 <= total) {
            int i0 = buf[j], i1 = buf[j+1], i2 = buf[j+2], i3 = buf[j+3];
            a0 += loadx(z, i0 * IN_DIM + lane, f32) * g_dinv[i0];
            a1 += loadx(z, i1 * IN_DIM + lane, f32) * g_dinv[i1];
            a2 += loadx(z, i2 * IN_DIM + lane, f32) * g_dinv[i2];
            a3 += loadx(z, i3 * IN_DIM + lane, f32) * g_dinv[i3];
            j += 4;
        }
        for (; j < total; j++) {
            int i0 = buf[j];
            a0 += loadx(z, i0 * IN_DIM + lane, f32) * g_dinv[i0];
        }
    } else {  // rare fallback: serial 8-range walk
        for (int g = 0; g < NGRP; g++) {
            int beg = g_rowptr8[g * N + wid], end = g_rowptr8[g * N + wid + 1];
            for (int e = beg; e < end; e++) {
                int s = g_csr[e];
                a0 += loadx(z, s * IN_DIM + lane, f32) * g_dinv[s];
            }
        }
    }
    float acc = ((a0 + a1) + (a2 + a3)) + ((a4 + a5) + (a6 + a7));
    g_hs1[(size_t)wid * 64 + lane] = acc * g_dinv[wid];
}

// ---- h = relu(aggz @ W1 + b1): 32 rows/block, 4x4 micro-tile, W from L1/L2 ----
__global__ __launch_bounds__(256) void gemm1_kernel(int N) {
    __shared__ float Zs[IN_DIM * 33];  // transposed 64k x 32r, pad 33 -> 8448 B
    int t = threadIdx.x;
    int row0 = blockIdx.x * 32;
    const float* aggz = g_hs1;
#pragma unroll
    for (int s = 0; s < 2; s++) {
        int i = t + s * 256;          // 512 float4s = 32 rows x 16
        int r = i >> 4, k4 = i & 15;
        int row = row0 + r;
        float4 v = make_float4(0.f, 0.f, 0.f, 0.f);
        if (row < N) v = *(const float4*)&aggz[(size_t)row * IN_DIM + k4 * 4];
        Zs[(k4 * 4 + 0) * 33 + r] = v.x;
        Zs[(k4 * 4 + 1) * 33 + r] = v.y;
        Zs[(k4 * 4 + 2) * 33 + r] = v.z;
        Zs[(k4 * 4 + 3) * 33 + r] = v.w;
    }
    __syncthreads();
    int cg = t & 31, rg = t >> 5;  // 32 colgroups x 8 rowgroups
    int c0 = cg * 4, r0 = rg * 4;
    float acc[4][4] = {};
#pragma unroll 8
    for (int k = 0; k < IN_DIM; k++) {
        float b[4];
        *(float4*)b = *(const float4*)&g_W1f[k * HID_DIM + c0];
        float a[4];
        a[0] = Zs[k * 33 + r0];
        a[1] = Zs[k * 33 + r0 + 1];
        a[2] = Zs[k * 33 + r0 + 2];
        a[3] = Zs[k * 33 + r0 + 3];
#pragma unroll
        for (int i = 0; i < 4; i++)
#pragma unroll
            for (int j = 0; j < 4; j++) acc[i][j] = fmaf(a[i], b[j], acc[i][j]);
    }
    float4 bias = *(const float4*)&g_b1f[c0];
#pragma unroll
    for (int i = 0; i < 4; i++) {
        int row = row0 + r0 + i;
        if (row < N) {
            float4 v;
            v.x = fmaxf(acc[i][0] + bias.x, 0.f);
            v.y = fmaxf(acc[i][1] + bias.y, 0.f);
            v.z = fmaxf(acc[i][2] + bias.z, 0.f);
            v.w = fmaxf(acc[i][3] + bias.w, 0.f);
            *(float4*)&g_agg1[(size_t)row * HID_DIM + c0] = v;
        }
    }
}

// ---- hs2 = (h @ W2) * dinv: 32 rows/block, 2x4 micro-tile, K split 2x64 ----
__global__ __launch_bounds__(256) void gemm2_kernel(int N) {
    __shared__ float Zs[64 * 33];  // transposed 64k x 32r, pad 33 -> 8448 B
    int t = threadIdx.x;
    int row0 = blockIdx.x * 32;
    int cg = t & 15, rg = t >> 4;  // 16 colgroups x 16 rowgroups
    int c0 = cg * 4, r0 = rg * 2;
    float acc[2][4] = {};
    for (int kh = 0; kh < 2; kh++) {
        __syncthreads();
#pragma unroll
        for (int s = 0; s < 2; s++) {
            int i = t + s * 256;      // 512 float4s = 32 rows x 16
            int r = i >> 4, k4 = i & 15;
            int row = row0 + r;
            float4 v = make_float4(0.f, 0.f, 0.f, 0.f);
            if (row < N) v = *(const float4*)&g_agg1[(size_t)row * HID_DIM + kh * 64 + k4 * 4];
            Zs[(k4 * 4 + 0) * 33 + r] = v.x;
            Zs[(k4 * 4 + 1) * 33 + r] = v.y;
            Zs[(k4 * 4 + 2) * 33 + r] = v.z;
            Zs[(k4 * 4 + 3) * 33 + r] = v.w;
        }
        __syncthreads();
#pragma unroll 8
        for (int k2 = 0; k2 < 64; k2++) {
            float b[4];
            *(float4*)b = *(const float4*)&g_W2f[(kh * 64 + k2) * OUT_DIM + c0];
            float a[2];
            a[0] = Zs[k2 * 33 + r0];
            a[1] = Zs[k2 * 33 + r0 + 1];
#pragma unroll
            for (int i = 0; i < 2; i++)
#pragma unroll
                for (int j = 0; j < 4; j++) acc[i][j] = fmaf(a[i], b[j], acc[i][j]);
        }
    }
#pragma unroll
    for (int i = 0; i < 2; i++) {
        int row = row0 + r0 + i;
        if (row < N) {
            float dn = g_dinv[row];
            float4 v;
            v.x = acc[i][0] * dn;
            v.y = acc[i][1] * dn;
            v.z = acc[i][2] * dn;
            v.w = acc[i][3] * dn;
            *(float4*)&g_hs1[(size_t)row * OUT_DIM + c0] = v;
        }
    }
}

// ---- layer-2 aggregation: same compaction scheme; fused bias + store ----
__global__ __launch_bounds__(256) void agg2_kernel(void* __restrict__ out, int N) {
    __shared__ int idxbuf[4][MAXE];
    int wid = (blockIdx.x * blockDim.x + threadIdx.x) >> 6;
    if (wid >= N) return;
    int lane = threadIdx.x & 63;
    int w = threadIdx.x >> 6;
    const float* hs = g_hs1;  // row = 64 floats (already dinv-scaled)
    int mybeg = 0, mycnt = 0;
    if (lane < NGRP) {
        mybeg = g_rowptr8[lane * N + wid];
        mycnt = g_rowptr8[lane * N + wid + 1] - mybeg;
    }
    int incl = mycnt;
#pragma unroll
    for (int off = 1; off < NGRP; off <<= 1) {
        int v = __shfl_up(incl, off, 64);
        if (lane >= off) incl += v;
    }
    int total = __shfl(incl, NGRP - 1, 64);
    int myoff = incl - mycnt;
    int* buf = idxbuf[w];
    float a0 = hs[(size_t)wid * 64 + lane];  // self loop
    float a1 = 0.f, a2 = 0.f, a3 = 0.f, a4 = 0.f, a5 = 0.f, a6 = 0.f, a7 = 0.f;
    if (total <= MAXE) {
        if (lane < NGRP) {
            for (int i = 0; i < mycnt; i++) buf[myoff + i] = g_csr[mybeg + i];
        }
        int j = 0;
        for (; j + 8 <= total; j += 8) {
            int i0 = buf[j], i1 = buf[j+1], i2 = buf[j+2], i3 = buf[j+3];
            int i4 = buf[j+4], i5 = buf[j+5], i6 = buf[j+6], i7 = buf[j+7];
            a0 += hs[(size_t)i0 * 64 + lane];
            a1 += hs[(size_t)i1 * 64 + lane];
            a2 += hs[(size_t)i2 * 64 + lane];
            a3 += hs[(size_t)i3 * 64 + lane];
            a4 += hs[(size_t)i4 * 64 + lane];
            a5 += hs[(size_t)i5 * 64 + lane];
            a6 += hs[(size_t)i6 * 64 + lane];
            a7 += hs[(size_t)i7 * 64 + lane];
        }
        if (j + 4 <= total) {
            int i0 = buf[j], i1 = buf[j+1], i2 = buf[j+2], i3 = buf[j+3];
            a0 += hs[(size_t)i0 * 64 + lane];
            a1 += hs[(size_t)i1 * 64 + lane];
            a2 += hs[(size_t)i2 * 64 + lane];
            a3 += hs[(size_t)i3 * 64 + lane];
            j += 4;
        }
        for (; j < total; j++) a0 += hs[(size_t)buf[j] * 64 + lane];
    } else {
        for (int g = 0; g < NGRP; g++) {
            int beg = g_rowptr8[g * N + wid], end = g_rowptr8[g * N + wid + 1];
            for (int e = beg; e < end; e++) a0 += hs[(size_t)g_csr[e] * 64 + lane];
        }
    }
    float acc = ((a0 + a1) + (a2 + a3)) + ((a4 + a5) + (a6 + a7));
    float v = acc * g_dinv[wid] + g_b2f[lane];
    if (g_in_f32) ((float*)out)[(size_t)wid * 64 + lane] = v;
    else ((__hip_bfloat16*)out)[(size_t)wid * 64 + lane] = __float2bfloat16(v);
}

extern "C" void kernel_launch(void* const* d_in, const int* in_sizes, int n_in,
                              void* d_out, int out_size, void* d_ws, size_t ws_size,
                              hipStream_t stream) {
    const void* z  = d_in[0];
    const void* ei = d_in[1];
    const void* W1 = d_in[2];
    const void* b1 = d_in[3];
    const void* W2 = d_in[4];
    const void* b2 = d_in[5];

    const int N = in_sizes[0] / IN_DIM;  // 50000
    const int E = in_sizes[1] / 2;       // 800000
    const int NE = NGRP * N;             // 400000

    detect_kernel<<<1, 256, 0, stream>>>((const unsigned short*)z, (const unsigned int*)ei, E);
    prep_kernel<<<NBLK8, 256, 0, stream>>>(W1, b1, W2, b2);
    convert_kernel<<<(E + 255) / 256, 256, 0, stream>>>(ei, N, E);
    dinv_kernel<<<(N + 255) / 256, 256, 0, stream>>>(N);
    localscan_kernel<<<(NE + 255) / 256, 256, 0, stream>>>(NE);
    bscan_kernel<<<1, 256, 0, stream>>>((NE + 255) / 256, NE, E);
    addoff_kernel<<<(NE + 255) / 256, 256, 0, stream>>>(NE);
    scatter_kernel<<<(E + 255) / 256, 256, 0, stream>>>(N, E);

    aggz_kernel<<<(N * 64 + 255) / 256, 256, 0, stream>>>(z, N);
    gemm1_kernel<<<(N + 31) / 32, 256, 0, stream>>>(N);
    gemm2_kernel<<<(N + 31) / 32, 256, 0, stream>>>(N);
    agg2_kernel<<<(N * 64 + 255) / 256, 256, 0, stream>>>(d_out, N);
}